// Round 12
// baseline (149.688 us; speedup 1.0000x reference)
//
#include <hip/hip_runtime.h>

typedef unsigned short u16;
typedef unsigned int u32;
typedef _Float16 h8 __attribute__((ext_vector_type(8)));
typedef __fp16 fp16x2 __attribute__((ext_vector_type(2)));
typedef float f32x16 __attribute__((ext_vector_type(16)));

__device__ inline f32x16 zero16() {
    f32x16 v;
#pragma unroll
    for (int i = 0; i < 16; ++i) v[i] = 0.f;
    return v;
}
__device__ inline u16 f2h_bits(float f) {
    _Float16 h = (_Float16)f;
    u16 u;
    __builtin_memcpy(&u, &h, 2);
    return u;
}
__device__ inline void load_lds16(const u16* g, u16* l) {
    __builtin_amdgcn_global_load_lds((const __attribute__((address_space(1))) u32*)(const void*)g,
                                     (__attribute__((address_space(3))) u32*)(void*)l, 16, 0, 0);
}

// ---------- merged prep: X f32->f16 (blocks 0..2047), W f32 [1024][3072] -> Wt f16 [3072][1024] ----------
__global__ void __launch_bounds__(256) prep(const float* __restrict__ X, const float* __restrict__ W,
                                            u16* __restrict__ Xh, u16* __restrict__ Wt) {
    __shared__ __attribute__((aligned(16))) u16 tile[64][72];
    int bb = blockIdx.x;
    int tid = threadIdx.x;
    if (bb < 2048) {
        int i = (bb * 256 + tid) * 8;
        float4 a = *(const float4*)(X + i);
        float4 b = *(const float4*)(X + i + 4);
        u16 t[8] = {f2h_bits(a.x), f2h_bits(a.y), f2h_bits(a.z), f2h_bits(a.w),
                    f2h_bits(b.x), f2h_bits(b.y), f2h_bits(b.z), f2h_bits(b.w)};
        *(uint4*)(Xh + i) = *(uint4*)t;
        return;
    }
    bb -= 2048;
    int tn0 = (bb % 48) * 64, tk0 = (bb / 48) * 64;
#pragma unroll
    for (int i = 0; i < 4; ++i) {
        int e = (i * 256 + tid) * 4;
        int r = e >> 6, c = e & 63;
        float4 v = *(const float4*)(W + (size_t)(tk0 + r) * 3072 + tn0 + c);
        tile[r][c + 0] = f2h_bits(v.x);
        tile[r][c + 1] = f2h_bits(v.y);
        tile[r][c + 2] = f2h_bits(v.z);
        tile[r][c + 3] = f2h_bits(v.w);
    }
    __syncthreads();
#pragma unroll
    for (int i = 0; i < 2; ++i) {
        int e = (i * 256 + tid) * 8;
        int r = e >> 6, c = e & 63;
        u16 tmp[8];
#pragma unroll
        for (int j = 0; j < 8; ++j) tmp[j] = tile[c + j][r];
        *(uint4*)(Wt + (size_t)(tn0 + r) * 1024 + tk0 + c) = *(uint4*)tmp;
    }
}

// ---------- QKV GEMM with XOR-swizzled LDS; Q/K/V all in fragment-native tiled layouts ----------
// Qf[bh][qt][gc=d>>3][row=t&31][c=d&7]  (Q pre-scaled by 0.125)
// Kf[bh][kt][gc=d>>3][row=t&31][c=d&7]
// Vf[bh][kt][gc2=(t&31)>>3][d][c=t&7]
__global__ void __launch_bounds__(256) qkv_gemm(const u16* __restrict__ Xh, const u16* __restrict__ Wt,
                                                const float* __restrict__ bias, u16* __restrict__ Qf,
                                                u16* __restrict__ Kf, u16* __restrict__ Vf) {
    __shared__ __attribute__((aligned(16))) u16 As[128 * 32];
    __shared__ __attribute__((aligned(16))) u16 Bs[128 * 32];
    int m0 = blockIdx.x * 128, n0 = blockIdx.y * 128;
    int tid = threadIdx.x, wave = tid >> 6, lane = tid & 63;
    int lane31 = lane & 31, half = lane >> 5;
    int wm = wave & 1, wn = wave >> 1;
    int sw = (lane31 >> 1) & 3;

    f32x16 acc00 = zero16(), acc01 = zero16(), acc10 = zero16(), acc11 = zero16();

    for (int k0 = 0; k0 < 1024; k0 += 32) {
        __syncthreads();
#pragma unroll
        for (int i = 0; i < 2; ++i) {
            int e = (i * 256 + tid) * 8;
            int r = e >> 5, c = e & 31;
            int gs = ((c >> 3) ^ ((r >> 1) & 3)) * 8;
            load_lds16(Xh + (size_t)(m0 + r) * 1024 + k0 + gs, &As[e]);
            load_lds16(Wt + (size_t)(n0 + r) * 1024 + k0 + gs, &Bs[e]);
        }
        __syncthreads();
#pragma unroll
        for (int kk = 0; kk < 2; ++kk) {
            int ga = ((kk * 2 + half) ^ sw) * 8;
            h8 a0 = *(const h8*)&As[(wm * 64 + lane31) * 32 + ga];
            h8 a1 = *(const h8*)&As[(wm * 64 + 32 + lane31) * 32 + ga];
            h8 b0 = *(const h8*)&Bs[(wn * 64 + lane31) * 32 + ga];
            h8 b1 = *(const h8*)&Bs[(wn * 64 + 32 + lane31) * 32 + ga];
            acc00 = __builtin_amdgcn_mfma_f32_32x32x16_f16(a0, b0, acc00, 0, 0, 0);
            acc01 = __builtin_amdgcn_mfma_f32_32x32x16_f16(a0, b1, acc01, 0, 0, 0);
            acc10 = __builtin_amdgcn_mfma_f32_32x32x16_f16(a1, b0, acc10, 0, 0, 0);
            acc11 = __builtin_amdgcn_mfma_f32_32x32x16_f16(a1, b1, acc11, 0, 0, 0);
        }
    }

#pragma unroll
    for (int mi = 0; mi < 2; ++mi) {
#pragma unroll
        for (int ni = 0; ni < 2; ++ni) {
            const f32x16& acc = mi == 0 ? (ni == 0 ? acc00 : acc01) : (ni == 0 ? acc10 : acc11);
            int n = n0 + wn * 64 + ni * 32 + lane31;
            int mbase = m0 + wm * 64 + mi * 32;
            int bb = mbase >> 11, tb = mbase & 2047;
            float bv = bias[n];
            int n2 = n & 1023;
            int h = n2 >> 6, d = n2 & 63;
            if (n < 2048) {
                // Q and K share the fragment-native layout; Q gets the 0.125 scale
                float sc = (n < 1024) ? 0.125f : 1.0f;
                u16* base = (n < 1024 ? Qf : Kf) +
                            (size_t)(bb * 16 + h) * 131072 + (tb >> 5) * 2048 + (d >> 3) * 256 + (d & 7);
#pragma unroll
                for (int r = 0; r < 16; ++r) {
                    int row = (r & 3) + 8 * (r >> 2) + 4 * half;
                    base[row * 8] = f2h_bits((acc[r] + bv) * sc);
                }
            } else {
                u16* vbase = Vf + (size_t)(bb * 16 + h) * 131072 + (tb >> 5) * 2048 + d * 8 + 4 * half;
#pragma unroll
                for (int rq = 0; rq < 4; ++rq) {
                    u16 q4[4];
#pragma unroll
                    for (int j = 0; j < 4; ++j) q4[j] = f2h_bits(acc[4 * rq + j] + bv);
                    *(ushort4*)(vbase + rq * 512) = *(ushort4*)q4;
                }
            }
        }
    }
}

// ---------- attention v5: all operands fragment-native, 4-way split-K ----------
__global__ void __launch_bounds__(256) attn(const u16* __restrict__ Qf, const u16* __restrict__ Kf,
                                            const u16* __restrict__ Vf, float* __restrict__ out) {
    __shared__ float4 red[3 * 8 * 64];  // 24 KB
    int bh = blockIdx.x;                // fast dim -> same-bh blocks share an XCD
    int p = blockIdx.y;
    int b = bh >> 4, h = bh & 15;
    int tid = threadIdx.x, w = tid >> 6, lane = tid & 63;
    int l31 = lane & 31, half = lane >> 5;
    int tiles2[2] = {p, 63 - p};

    const u16* Qbh = Qf + (size_t)bh * 131072;
    const u16* Kbh = Kf + (size_t)bh * 131072;
    const u16* Vbh = Vf + (size_t)bh * 131072;

#pragma unroll
    for (int s = 0; s < 2; ++s) {
        int tt = tiles2[s];
        int qset = tt * 32;
        const u16* qp = Qbh + tt * 2048 + half * 256 + l31 * 8;  // fragment-native
        h8 aQ[4];
#pragma unroll
        for (int kk = 0; kk < 4; ++kk) aQ[kk] = *(const h8*)(qp + kk * 512);

        int nkt = tt + 1;
        int kt0 = (nkt * w) >> 2;
        int kt1 = (nkt * (w + 1)) >> 2;
        f32x16 y0 = zero16(), y1 = zero16();
        int qg = qset + l31;

        if (kt0 < kt1) {
            const u16* kp = Kbh + kt0 * 2048 + half * 256 + l31 * 8;
            const u16* vp = Vbh + kt0 * 2048 + half * 512 + l31 * 8;
            h8 cK[4], cV[4];
#pragma unroll
            for (int kk = 0; kk < 4; ++kk) cK[kk] = *(const h8*)(kp + kk * 512);
            cV[0] = *(const h8*)vp;
            cV[1] = *(const h8*)(vp + 1024);
            cV[2] = *(const h8*)(vp + 256);
            cV[3] = *(const h8*)(vp + 1280);

            for (int kt = kt0; kt < kt1; ++kt) {
                int kbase = kt * 32;
                int ktn = kt + 1 < kt1 ? kt + 1 : kt1 - 1;
                const u16* kpn = Kbh + ktn * 2048 + half * 256 + l31 * 8;
                const u16* vpn = Vbh + ktn * 2048 + half * 512 + l31 * 8;
                h8 nK[4], nV[4];
#pragma unroll
                for (int kk = 0; kk < 4; ++kk) nK[kk] = *(const h8*)(kpn + kk * 512);
                nV[0] = *(const h8*)vpn;
                nV[1] = *(const h8*)(vpn + 1024);
                nV[2] = *(const h8*)(vpn + 256);
                nV[3] = *(const h8*)(vpn + 1280);

                f32x16 sT = zero16();
#pragma unroll
                for (int kk = 0; kk < 4; ++kk)
                    sT = __builtin_amdgcn_mfma_f32_32x32x16_f16(cK[kk], aQ[kk], sT, 0, 0, 0);

                int cbase = qg - kbase - 4 * half;
                u32 pk[8];
#pragma unroll
                for (int j = 0; j < 8; ++j) {
                    int row0 = ((2 * j) & 3) + 8 * (j >> 1);
                    float v0 = (row0 <= cbase) ? fmaxf(sT[2 * j], 0.f) : 0.f;
                    float v1 = (row0 + 1 <= cbase) ? fmaxf(sT[2 * j + 1], 0.f) : 0.f;
                    fp16x2 c2 = __builtin_amdgcn_cvt_pkrtz(v0, v1);
                    __builtin_memcpy(&pk[j], &c2, 4);
                }
                u32 x[8];
#pragma unroll
                for (int j = 0; j < 8; ++j) x[j] = (u32)__shfl_xor((int)pk[j], 32);
                u32 f0[4], f1[4];
                bool hi = (half != 0);
                f0[0] = hi ? x[2] : pk[0];
                f0[1] = hi ? x[3] : pk[1];
                f0[2] = hi ? pk[2] : x[0];
                f0[3] = hi ? pk[3] : x[1];
                f1[0] = hi ? x[6] : pk[4];
                f1[1] = hi ? x[7] : pk[5];
                f1[2] = hi ? pk[6] : x[4];
                f1[3] = hi ? pk[7] : x[5];
                h8 bP0, bP1;
                __builtin_memcpy(&bP0, f0, 16);
                __builtin_memcpy(&bP1, f1, 16);

                y0 = __builtin_amdgcn_mfma_f32_32x32x16_f16(cV[0], bP0, y0, 0, 0, 0);
                y0 = __builtin_amdgcn_mfma_f32_32x32x16_f16(cV[1], bP1, y0, 0, 0, 0);
                y1 = __builtin_amdgcn_mfma_f32_32x32x16_f16(cV[2], bP0, y1, 0, 0, 0);
                y1 = __builtin_amdgcn_mfma_f32_32x32x16_f16(cV[3], bP1, y1, 0, 0, 0);

#pragma unroll
                for (int kk = 0; kk < 4; ++kk) {
                    cK[kk] = nK[kk];
                    cV[kk] = nV[kk];
                }
            }
        }

        if (w > 0) {
#pragma unroll
            for (int g = 0; g < 4; ++g) {
                red[((w - 1) * 8 + g) * 64 + lane] =
                    make_float4(y0[4 * g], y0[4 * g + 1], y0[4 * g + 2], y0[4 * g + 3]);
                red[((w - 1) * 8 + 4 + g) * 64 + lane] =
                    make_float4(y1[4 * g], y1[4 * g + 1], y1[4 * g + 2], y1[4 * g + 3]);
            }
        }
        __syncthreads();
        if (w == 0) {
#pragma unroll
            for (int j = 0; j < 3; ++j)
#pragma unroll
                for (int g = 0; g < 4; ++g) {
                    float4 a0 = red[(j * 8 + g) * 64 + lane];
                    float4 a1 = red[(j * 8 + 4 + g) * 64 + lane];
                    y0[4 * g] += a0.x; y0[4 * g + 1] += a0.y; y0[4 * g + 2] += a0.z; y0[4 * g + 3] += a0.w;
                    y1[4 * g] += a1.x; y1[4 * g + 1] += a1.y; y1[4 * g + 2] += a1.z; y1[4 * g + 3] += a1.w;
                }
            int qrow = qset + l31;
            float* orow = out + ((size_t)b * 2048 + qrow) * 1024 + h * 64;
#pragma unroll
            for (int g = 0; g < 4; ++g) {
                int d = 8 * g + 4 * half;
                *(float4*)(orow + d) = make_float4(y0[4 * g], y0[4 * g + 1], y0[4 * g + 2], y0[4 * g + 3]);
                *(float4*)(orow + 32 + d) = make_float4(y1[4 * g], y1[4 * g + 1], y1[4 * g + 2], y1[4 * g + 3]);
            }
        }
        __syncthreads();
    }
}

extern "C" void kernel_launch(void* const* d_in, const int* in_sizes, int n_in,
                              void* d_out, int out_size, void* d_ws, size_t ws_size,
                              hipStream_t stream) {
    const float* X = (const float*)d_in[0];     // [2,2048,1024] f32 (fp16 values widened)
    const float* W = (const float*)d_in[1];     // [1024,3072] f32
    const float* bias = (const float*)d_in[2];  // [3072] f32
    float* out = (float*)d_out;                 // [2,2048,1024] f32

    char* ws = (char*)d_ws;
    u16* Xh = (u16*)ws;                      // 8388608 B
    u16* Wt = (u16*)(ws + 8388608);          // 6291456 B
    u16* Qf = (u16*)(ws + 14680064);         // 8388608 B
    u16* Kf = (u16*)(ws + 23068672);         // 8388608 B
    u16* Vf = (u16*)(ws + 31457280);         // 8388608 B

    prep<<<2816, 256, 0, stream>>>(X, W, Xh, Wt);
    qkv_gemm<<<dim3(32, 24), 256, 0, stream>>>(Xh, Wt, bias, Qf, Kf, Vf);
    attn<<<dim3(32, 32), 256, 0, stream>>>(Qf, Kf, Vf, out);
}

// Round 13
// 143.488 us; speedup vs baseline: 1.0432x; 1.0432x over previous
//
#include <hip/hip_runtime.h>

typedef unsigned short u16;
typedef unsigned int u32;
typedef _Float16 h8 __attribute__((ext_vector_type(8)));
typedef __fp16 fp16x2 __attribute__((ext_vector_type(2)));
typedef float f32x16 __attribute__((ext_vector_type(16)));

__device__ inline f32x16 zero16() {
    f32x16 v;
#pragma unroll
    for (int i = 0; i < 16; ++i) v[i] = 0.f;
    return v;
}
__device__ inline u16 f2h_bits(float f) {
    _Float16 h = (_Float16)f;
    u16 u;
    __builtin_memcpy(&u, &h, 2);
    return u;
}
__device__ inline void load_lds16(const u16* g, u16* l) {
    __builtin_amdgcn_global_load_lds((const __attribute__((address_space(1))) u32*)(const void*)g,
                                     (__attribute__((address_space(3))) u32*)(void*)l, 16, 0, 0);
}

// ---------- merged prep: X f32->f16 (blocks 0..2047), W f32 [1024][3072] -> Wt f16 [3072][1024] ----------
__global__ void __launch_bounds__(256) prep(const float* __restrict__ X, const float* __restrict__ W,
                                            u16* __restrict__ Xh, u16* __restrict__ Wt) {
    __shared__ __attribute__((aligned(16))) u16 tile[64][72];
    int bb = blockIdx.x;
    int tid = threadIdx.x;
    if (bb < 2048) {
        int i = (bb * 256 + tid) * 8;
        float4 a = *(const float4*)(X + i);
        float4 b = *(const float4*)(X + i + 4);
        u16 t[8] = {f2h_bits(a.x), f2h_bits(a.y), f2h_bits(a.z), f2h_bits(a.w),
                    f2h_bits(b.x), f2h_bits(b.y), f2h_bits(b.z), f2h_bits(b.w)};
        *(uint4*)(Xh + i) = *(uint4*)t;
        return;
    }
    bb -= 2048;
    int tn0 = (bb % 48) * 64, tk0 = (bb / 48) * 64;
#pragma unroll
    for (int i = 0; i < 4; ++i) {
        int e = (i * 256 + tid) * 4;
        int r = e >> 6, c = e & 63;
        float4 v = *(const float4*)(W + (size_t)(tk0 + r) * 3072 + tn0 + c);
        tile[r][c + 0] = f2h_bits(v.x);
        tile[r][c + 1] = f2h_bits(v.y);
        tile[r][c + 2] = f2h_bits(v.z);
        tile[r][c + 3] = f2h_bits(v.w);
    }
    __syncthreads();
#pragma unroll
    for (int i = 0; i < 2; ++i) {
        int e = (i * 256 + tid) * 8;
        int r = e >> 6, c = e & 63;
        u16 tmp[8];
#pragma unroll
        for (int j = 0; j < 8; ++j) tmp[j] = tile[c + j][r];
        *(uint4*)(Wt + (size_t)(tn0 + r) * 1024 + tk0 + c) = *(uint4*)tmp;
    }
}

// ---------- QKV GEMM, BK=64 (half the barrier drains), XOR-swizzled LDS ----------
// Qf/Kf[bh][kt][gc=d>>3][row=t&31][c=d&7]  (Q pre-scaled by 0.125)
// Vf[bh][kt][gc2=(t&31)>>3][d][c=t&7]
__global__ void __launch_bounds__(256) qkv_gemm(const u16* __restrict__ Xh, const u16* __restrict__ Wt,
                                                const float* __restrict__ bias, u16* __restrict__ Qf,
                                                u16* __restrict__ Kf, u16* __restrict__ Vf) {
    __shared__ __attribute__((aligned(16))) u16 As[128 * 64];  // 16 KB
    __shared__ __attribute__((aligned(16))) u16 Bs[128 * 64];  // 16 KB
    int m0 = blockIdx.x * 128, n0 = blockIdx.y * 128;
    int tid = threadIdx.x, wave = tid >> 6, lane = tid & 63;
    int lane31 = lane & 31, half = lane >> 5;
    int wm = wave & 1, wn = wave >> 1;
    int sw = (lane31 >> 1) & 7;  // 3-bit swizzle; rows +32/+64 shift by 0 mod 8 after >>1

    f32x16 acc00 = zero16(), acc01 = zero16(), acc10 = zero16(), acc11 = zero16();

    for (int k0 = 0; k0 < 1024; k0 += 64) {
        __syncthreads();
#pragma unroll
        for (int i = 0; i < 4; ++i) {
            int e = (i * 256 + tid) * 8;  // [0, 8192)
            int r = e >> 6, c = e & 63;
            int gs = ((c >> 3) ^ ((r >> 1) & 7)) * 8;
            load_lds16(Xh + (size_t)(m0 + r) * 1024 + k0 + gs, &As[e]);
            load_lds16(Wt + (size_t)(n0 + r) * 1024 + k0 + gs, &Bs[e]);
        }
        __syncthreads();
#pragma unroll
        for (int kk = 0; kk < 4; ++kk) {
            int ga = ((kk * 2 + half) ^ sw) * 8;
            h8 a0 = *(const h8*)&As[(wm * 64 + lane31) * 64 + ga];
            h8 a1 = *(const h8*)&As[(wm * 64 + 32 + lane31) * 64 + ga];
            h8 b0 = *(const h8*)&Bs[(wn * 64 + lane31) * 64 + ga];
            h8 b1 = *(const h8*)&Bs[(wn * 64 + 32 + lane31) * 64 + ga];
            acc00 = __builtin_amdgcn_mfma_f32_32x32x16_f16(a0, b0, acc00, 0, 0, 0);
            acc01 = __builtin_amdgcn_mfma_f32_32x32x16_f16(a0, b1, acc01, 0, 0, 0);
            acc10 = __builtin_amdgcn_mfma_f32_32x32x16_f16(a1, b0, acc10, 0, 0, 0);
            acc11 = __builtin_amdgcn_mfma_f32_32x32x16_f16(a1, b1, acc11, 0, 0, 0);
        }
    }

#pragma unroll
    for (int mi = 0; mi < 2; ++mi) {
#pragma unroll
        for (int ni = 0; ni < 2; ++ni) {
            const f32x16& acc = mi == 0 ? (ni == 0 ? acc00 : acc01) : (ni == 0 ? acc10 : acc11);
            int n = n0 + wn * 64 + ni * 32 + lane31;
            int mbase = m0 + wm * 64 + mi * 32;
            int bb = mbase >> 11, tb = mbase & 2047;
            float bv = bias[n];
            int n2 = n & 1023;
            int h = n2 >> 6, d = n2 & 63;
            if (n < 2048) {
                float sc = (n < 1024) ? 0.125f : 1.0f;
                u16* base = (n < 1024 ? Qf : Kf) +
                            (size_t)(bb * 16 + h) * 131072 + (tb >> 5) * 2048 + (d >> 3) * 256 + (d & 7);
#pragma unroll
                for (int r = 0; r < 16; ++r) {
                    int row = (r & 3) + 8 * (r >> 2) + 4 * half;
                    base[row * 8] = f2h_bits((acc[r] + bv) * sc);
                }
            } else {
                u16* vbase = Vf + (size_t)(bb * 16 + h) * 131072 + (tb >> 5) * 2048 + d * 8 + 4 * half;
#pragma unroll
                for (int rq = 0; rq < 4; ++rq) {
                    u16 q4[4];
#pragma unroll
                    for (int j = 0; j < 4; ++j) q4[j] = f2h_bits(acc[4 * rq + j] + bv);
                    *(ushort4*)(vbase + rq * 512) = *(ushort4*)q4;
                }
            }
        }
    }
}

// ---------- attention v6: single-tile blocks (2x TLP), fragment-native operands, 4-way split-K ----------
__global__ void __launch_bounds__(256) attn(const u16* __restrict__ Qf, const u16* __restrict__ Kf,
                                            const u16* __restrict__ Vf, float* __restrict__ out) {
    __shared__ float4 red[3 * 8 * 64];  // 24 KB
    int bh = blockIdx.x;                // fast dim: id%8 = bh%8 -> same-bh on one XCD
    int tt = blockIdx.y;                // q-tile 0..63
    int b = bh >> 4, h = bh & 15;
    int tid = threadIdx.x, w = tid >> 6, lane = tid & 63;
    int l31 = lane & 31, half = lane >> 5;

    const u16* Qbh = Qf + (size_t)bh * 131072;
    const u16* Kbh = Kf + (size_t)bh * 131072;
    const u16* Vbh = Vf + (size_t)bh * 131072;

    int qset = tt * 32;
    const u16* qp = Qbh + tt * 2048 + half * 256 + l31 * 8;
    h8 aQ[4];
#pragma unroll
    for (int kk = 0; kk < 4; ++kk) aQ[kk] = *(const h8*)(qp + kk * 512);

    int nkt = tt + 1;
    int kt0 = (nkt * w) >> 2;
    int kt1 = (nkt * (w + 1)) >> 2;
    f32x16 y0 = zero16(), y1 = zero16();
    int qg = qset + l31;

    if (kt0 < kt1) {
        const u16* kp = Kbh + kt0 * 2048 + half * 256 + l31 * 8;
        const u16* vp = Vbh + kt0 * 2048 + half * 512 + l31 * 8;
        h8 cK[4], cV[4];
#pragma unroll
        for (int kk = 0; kk < 4; ++kk) cK[kk] = *(const h8*)(kp + kk * 512);
        cV[0] = *(const h8*)vp;
        cV[1] = *(const h8*)(vp + 1024);
        cV[2] = *(const h8*)(vp + 256);
        cV[3] = *(const h8*)(vp + 1280);

        for (int kt = kt0; kt < kt1; ++kt) {
            int kbase = kt * 32;
            int ktn = kt + 1 < kt1 ? kt + 1 : kt1 - 1;
            const u16* kpn = Kbh + ktn * 2048 + half * 256 + l31 * 8;
            const u16* vpn = Vbh + ktn * 2048 + half * 512 + l31 * 8;
            h8 nK[4], nV[4];
#pragma unroll
            for (int kk = 0; kk < 4; ++kk) nK[kk] = *(const h8*)(kpn + kk * 512);
            nV[0] = *(const h8*)vpn;
            nV[1] = *(const h8*)(vpn + 1024);
            nV[2] = *(const h8*)(vpn + 256);
            nV[3] = *(const h8*)(vpn + 1280);

            f32x16 sT = zero16();
#pragma unroll
            for (int kk = 0; kk < 4; ++kk)
                sT = __builtin_amdgcn_mfma_f32_32x32x16_f16(cK[kk], aQ[kk], sT, 0, 0, 0);

            int cbase = qg - kbase - 4 * half;
            u32 pk[8];
#pragma unroll
            for (int j = 0; j < 8; ++j) {
                int row0 = ((2 * j) & 3) + 8 * (j >> 1);
                float v0 = (row0 <= cbase) ? fmaxf(sT[2 * j], 0.f) : 0.f;
                float v1 = (row0 + 1 <= cbase) ? fmaxf(sT[2 * j + 1], 0.f) : 0.f;
                fp16x2 c2 = __builtin_amdgcn_cvt_pkrtz(v0, v1);
                __builtin_memcpy(&pk[j], &c2, 4);
            }
            u32 x[8];
#pragma unroll
            for (int j = 0; j < 8; ++j) x[j] = (u32)__shfl_xor((int)pk[j], 32);
            u32 f0[4], f1[4];
            bool hi = (half != 0);
            f0[0] = hi ? x[2] : pk[0];
            f0[1] = hi ? x[3] : pk[1];
            f0[2] = hi ? pk[2] : x[0];
            f0[3] = hi ? pk[3] : x[1];
            f1[0] = hi ? x[6] : pk[4];
            f1[1] = hi ? x[7] : pk[5];
            f1[2] = hi ? pk[6] : x[4];
            f1[3] = hi ? pk[7] : x[5];
            h8 bP0, bP1;
            __builtin_memcpy(&bP0, f0, 16);
            __builtin_memcpy(&bP1, f1, 16);

            y0 = __builtin_amdgcn_mfma_f32_32x32x16_f16(cV[0], bP0, y0, 0, 0, 0);
            y0 = __builtin_amdgcn_mfma_f32_32x32x16_f16(cV[1], bP1, y0, 0, 0, 0);
            y1 = __builtin_amdgcn_mfma_f32_32x32x16_f16(cV[2], bP0, y1, 0, 0, 0);
            y1 = __builtin_amdgcn_mfma_f32_32x32x16_f16(cV[3], bP1, y1, 0, 0, 0);

#pragma unroll
            for (int kk = 0; kk < 4; ++kk) {
                cK[kk] = nK[kk];
                cV[kk] = nV[kk];
            }
        }
    }

    if (w > 0) {
#pragma unroll
        for (int g = 0; g < 4; ++g) {
            red[((w - 1) * 8 + g) * 64 + lane] =
                make_float4(y0[4 * g], y0[4 * g + 1], y0[4 * g + 2], y0[4 * g + 3]);
            red[((w - 1) * 8 + 4 + g) * 64 + lane] =
                make_float4(y1[4 * g], y1[4 * g + 1], y1[4 * g + 2], y1[4 * g + 3]);
        }
    }
    __syncthreads();
    if (w == 0) {
#pragma unroll
        for (int j = 0; j < 3; ++j)
#pragma unroll
            for (int g = 0; g < 4; ++g) {
                float4 a0 = red[(j * 8 + g) * 64 + lane];
                float4 a1 = red[(j * 8 + 4 + g) * 64 + lane];
                y0[4 * g] += a0.x; y0[4 * g + 1] += a0.y; y0[4 * g + 2] += a0.z; y0[4 * g + 3] += a0.w;
                y1[4 * g] += a1.x; y1[4 * g + 1] += a1.y; y1[4 * g + 2] += a1.z; y1[4 * g + 3] += a1.w;
            }
        int qrow = qset + l31;
        float* orow = out + ((size_t)b * 2048 + qrow) * 1024 + h * 64;
#pragma unroll
        for (int g = 0; g < 4; ++g) {
            int d = 8 * g + 4 * half;
            *(float4*)(orow + d) = make_float4(y0[4 * g], y0[4 * g + 1], y0[4 * g + 2], y0[4 * g + 3]);
            *(float4*)(orow + 32 + d) = make_float4(y1[4 * g], y1[4 * g + 1], y1[4 * g + 2], y1[4 * g + 3]);
        }
    }
}

extern "C" void kernel_launch(void* const* d_in, const int* in_sizes, int n_in,
                              void* d_out, int out_size, void* d_ws, size_t ws_size,
                              hipStream_t stream) {
    const float* X = (const float*)d_in[0];     // [2,2048,1024] f32 (fp16 values widened)
    const float* W = (const float*)d_in[1];     // [1024,3072] f32
    const float* bias = (const float*)d_in[2];  // [3072] f32
    float* out = (float*)d_out;                 // [2,2048,1024] f32

    char* ws = (char*)d_ws;
    u16* Xh = (u16*)ws;                      // 8388608 B
    u16* Wt = (u16*)(ws + 8388608);          // 6291456 B
    u16* Qf = (u16*)(ws + 14680064);         // 8388608 B
    u16* Kf = (u16*)(ws + 23068672);         // 8388608 B
    u16* Vf = (u16*)(ws + 31457280);         // 8388608 B

    prep<<<2816, 256, 0, stream>>>(X, W, Xh, Wt);
    qkv_gemm<<<dim3(32, 24), 256, 0, stream>>>(Xh, Wt, bias, Qf, Kf, Vf);
    attn<<<dim3(32, 64), 256, 0, stream>>>(Qf, Kf, Vf, out);
}